// Round 1
// baseline (1352.699 us; speedup 1.0000x reference)
//
#include <hip/hip_runtime.h>

#define D 128
#define K_ORDER 6

__device__ __forceinline__ float silu_f(float x) {
    return x / (1.0f + __expf(-x));
}

// ---------------- CSR build ----------------

__global__ void count_deg_kernel(const int* __restrict__ dst, int* __restrict__ deg, int e) {
    int i = blockIdx.x * blockDim.x + threadIdx.x;
    if (i < e) atomicAdd(&deg[dst[i]], 1);
}

// single-block exclusive scan over n (~100k) ints -> row_ptr[0..n]
__global__ void scan_excl_kernel(const int* __restrict__ deg, int* __restrict__ row_ptr, int n) {
    __shared__ int lds[1024];
    __shared__ int carry_s;
    if (threadIdx.x == 0) carry_s = 0;
    __syncthreads();
    for (int base = 0; base < n; base += 1024) {
        int i = base + (int)threadIdx.x;
        int v = (i < n) ? deg[i] : 0;
        lds[threadIdx.x] = v;
        __syncthreads();
        // Hillis-Steele inclusive scan
        for (int off = 1; off < 1024; off <<= 1) {
            int t = (threadIdx.x >= (unsigned)off) ? lds[threadIdx.x - off] : 0;
            __syncthreads();
            lds[threadIdx.x] += t;
            __syncthreads();
        }
        int incl = lds[threadIdx.x];
        int carry = carry_s;
        if (i < n) row_ptr[i] = carry + incl - v;
        __syncthreads();
        if (threadIdx.x == 1023) carry_s = carry + incl;
        __syncthreads();
    }
    if (threadIdx.x == 0) row_ptr[n] = carry_s;
}

__global__ void scatter_edges_kernel(const int* __restrict__ src, const int* __restrict__ dst,
                                     const int* __restrict__ row_ptr, int* __restrict__ cursor,
                                     int* __restrict__ ssrc, int e) {
    int i = blockIdx.x * blockDim.x + threadIdx.x;
    if (i < e) {
        int d = dst[i];
        int p = row_ptr[d] + atomicAdd(&cursor[d], 1);
        ssrc[p] = src[i];
    }
}

// ---------------- GEMM (128x128 weights, LDS-cached) ----------------
// block = 256 threads, 32 rows per block. thread: row = tid>>3, col quad base = (tid&7)*4,
// computes cols {cq, cq+32, cq+64, cq+96} (4x float4 accumulators).
template <bool SILU, bool DUP>
__global__ __launch_bounds__(256) void gemm_fc_kernel(
        const float* __restrict__ A, const float* __restrict__ W,
        const float* __restrict__ bias, float* __restrict__ out,
        float* __restrict__ out2, int nrows) {
    __shared__ float sW[D * D];  // 64 KB
    {
        const float4* Wv = (const float4*)W;
        float4* sWv = (float4*)sW;
        for (int i = threadIdx.x; i < D * D / 4; i += 256) sWv[i] = Wv[i];
    }
    __syncthreads();

    int row = blockIdx.x * 32 + (threadIdx.x >> 3);
    if (row >= nrows) return;
    int cq = (threadIdx.x & 7) * 4;

    const float* Arow = A + (size_t)row * D;
    float4 acc[4] = {};

    for (int k = 0; k < D; k += 4) {
        float4 a4 = *(const float4*)(Arow + k);
        #pragma unroll
        for (int kk = 0; kk < 4; ++kk) {
            float a = ((const float*)&a4)[kk];
            const float* wr = sW + (k + kk) * D + cq;
            #pragma unroll
            for (int j = 0; j < 4; ++j) {
                float4 w = *(const float4*)(wr + j * 32);
                acc[j].x = fmaf(a, w.x, acc[j].x);
                acc[j].y = fmaf(a, w.y, acc[j].y);
                acc[j].z = fmaf(a, w.z, acc[j].z);
                acc[j].w = fmaf(a, w.w, acc[j].w);
            }
        }
    }

    size_t o = (size_t)row * D;
    #pragma unroll
    for (int j = 0; j < 4; ++j) {
        int c = cq + j * 32;
        float4 b = *(const float4*)(bias + c);
        float4 v;
        v.x = acc[j].x + b.x;
        v.y = acc[j].y + b.y;
        v.z = acc[j].z + b.z;
        v.w = acc[j].w + b.w;
        if (SILU) {
            v.x = silu_f(v.x); v.y = silu_f(v.y); v.z = silu_f(v.z); v.w = silu_f(v.w);
        }
        *(float4*)(out + o + c) = v;
        if (DUP) *(float4*)(out2 + o + c) = v;
    }
}

// ---------------- diffusion step ----------------
// one wave (64 lanes) per dst row; lane holds float2 (2 of 128 features).
__global__ __launch_bounds__(256) void diffuse_step_kernel(
        const float* __restrict__ term, float* __restrict__ next, float* __restrict__ acc,
        const int* __restrict__ row_ptr, const int* __restrict__ ssrc,
        float inv_i, int nrows) {
    int gw = blockIdx.x * 4 + (threadIdx.x >> 6);
    if (gw >= nrows) return;
    int lane = threadIdx.x & 63;

    int beg = row_ptr[gw];
    int end = row_ptr[gw + 1];
    int deg = end - beg;

    float2 s = make_float2(0.f, 0.f);
    int j = beg;
    for (; j + 1 < end; j += 2) {
        int s0 = ssrc[j];
        int s1 = ssrc[j + 1];
        float2 v0 = *(const float2*)(term + (size_t)s0 * D + lane * 2);
        float2 v1 = *(const float2*)(term + (size_t)s1 * D + lane * 2);
        s.x += v0.x + v1.x;
        s.y += v0.y + v1.y;
    }
    if (j < end) {
        int s0 = ssrc[j];
        float2 v0 = *(const float2*)(term + (size_t)s0 * D + lane * 2);
        s.x += v0.x;
        s.y += v0.y;
    }

    float scale = inv_i / (float)(deg > 1 ? deg : 1);
    size_t o = (size_t)gw * D + lane * 2;
    float2 t = make_float2(s.x * scale, s.y * scale);
    *(float2*)(next + o) = t;
    float2 a = *(const float2*)(acc + o);
    a.x += t.x;
    a.y += t.y;
    *(float2*)(acc + o) = a;
}

// ---------------- launch ----------------

extern "C" void kernel_launch(void* const* d_in, const int* in_sizes, int n_in,
                              void* d_out, int out_size, void* d_ws, size_t ws_size,
                              hipStream_t stream) {
    const float* h      = (const float*)d_in[0];
    const int*   eidx   = (const int*)d_in[1];
    const float* W_in   = (const float*)d_in[2];
    const float* b_in   = (const float*)d_in[3];
    const float* W1     = (const float*)d_in[4];
    const float* b1     = (const float*)d_in[5];
    const float* W2     = (const float*)d_in[6];
    const float* b2     = (const float*)d_in[7];
    float* out = (float*)d_out;

    const int N = in_sizes[0] / D;      // 100000
    const int E = in_sizes[1] / 2;      // 1600000

    const int* e_src = eidx;
    const int* e_dst = eidx + E;

    // workspace layout
    float* A = (float*)d_ws;                       // N*D floats (x / term ping)
    float* C = A + (size_t)N * D;                  // N*D floats (diffusion accumulator)
    int* deg     = (int*)(C + (size_t)N * D);      // N
    int* row_ptr = deg + N;                        // N+1
    int* cursor  = row_ptr + N + 1;                // N
    int* ssrc    = cursor + N;                     // E

    // zero deg + row_ptr + cursor in one shot
    hipMemsetAsync(deg, 0, sizeof(int) * (size_t)(3 * N + 1), stream);

    int eb = (E + 255) / 256;
    count_deg_kernel<<<eb, 256, 0, stream>>>(e_dst, deg, E);
    scan_excl_kernel<<<1, 1024, 0, stream>>>(deg, row_ptr, N);
    scatter_edges_kernel<<<eb, 256, 0, stream>>>(e_src, e_dst, row_ptr, cursor, ssrc, E);

    int gb = (N + 31) / 32;
    // x = silu(h @ W_in + b_in); write to A (term) and C (accumulator "out = x")
    gemm_fc_kernel<true, true><<<gb, 256, 0, stream>>>(h, W_in, b_in, A, C, N);

    // diffusion: term ping-pongs between A and d_out (d_out rewritten by final GEMM)
    float* term = A;
    float* nxt  = out;
    int db = (N + 3) / 4;
    for (int i = 1; i <= K_ORDER; ++i) {
        diffuse_step_kernel<<<db, 256, 0, stream>>>(term, nxt, C, row_ptr, ssrc,
                                                    1.0f / (float)i, N);
        float* tmp = term; term = nxt; nxt = tmp;
    }

    // x = silu(C @ W1 + b1) -> A
    gemm_fc_kernel<true, false><<<gb, 256, 0, stream>>>(C, W1, b1, A, nullptr, N);
    // out = A @ W2 + b2
    gemm_fc_kernel<false, false><<<gb, 256, 0, stream>>>(A, W2, b2, out, nullptr, N);
}

// Round 2
// 1166.761 us; speedup vs baseline: 1.1594x; 1.1594x over previous
//
#include <hip/hip_runtime.h>

#define D 128
#define K_ORDER 6

__device__ __forceinline__ float silu_f(float x) {
    return x / (1.0f + __expf(-x));
}

// ---------------- CSR build ----------------

__global__ void count_deg_kernel(const int* __restrict__ dst, int* __restrict__ deg, int e) {
    int i = blockIdx.x * blockDim.x + threadIdx.x;
    if (i < e) atomicAdd(&deg[dst[i]], 1);
}

// pass 1: per-block (512-wide) exclusive scan of deg -> row_ptr, block sums -> partials
__global__ __launch_bounds__(512) void scan_pass1_kernel(
        const int* __restrict__ deg, int* __restrict__ row_ptr,
        int* __restrict__ partials, int n) {
    __shared__ int lds[512];
    int i = blockIdx.x * 512 + threadIdx.x;
    int v = (i < n) ? deg[i] : 0;
    lds[threadIdx.x] = v;
    __syncthreads();
    #pragma unroll
    for (int off = 1; off < 512; off <<= 1) {
        int t = (threadIdx.x >= (unsigned)off) ? lds[threadIdx.x - off] : 0;
        __syncthreads();
        lds[threadIdx.x] += t;
        __syncthreads();
    }
    if (i < n) row_ptr[i] = lds[threadIdx.x] - v;   // exclusive
    if (threadIdx.x == 511) partials[blockIdx.x] = lds[511];
}

// pass 2: single block scans the (<=256) block sums into exclusive offsets
__global__ __launch_bounds__(256) void scan_pass2_kernel(int* __restrict__ partials, int np) {
    __shared__ int lds[256];
    int v = (threadIdx.x < (unsigned)np) ? partials[threadIdx.x] : 0;
    lds[threadIdx.x] = v;
    __syncthreads();
    #pragma unroll
    for (int off = 1; off < 256; off <<= 1) {
        int t = (threadIdx.x >= (unsigned)off) ? lds[threadIdx.x - off] : 0;
        __syncthreads();
        lds[threadIdx.x] += t;
        __syncthreads();
    }
    if (threadIdx.x < (unsigned)np) partials[threadIdx.x] = lds[threadIdx.x] - v;
}

// pass 3: add block offsets; also write row_ptr[n] = E
__global__ __launch_bounds__(512) void scan_pass3_kernel(
        int* __restrict__ row_ptr, const int* __restrict__ partials, int n, int e) {
    int i = blockIdx.x * 512 + threadIdx.x;
    if (i < n) row_ptr[i] += partials[blockIdx.x];
    if (i == n) row_ptr[n] = e;
}

__global__ void scatter_edges_kernel(const int* __restrict__ src, const int* __restrict__ dst,
                                     const int* __restrict__ row_ptr, int* __restrict__ cursor,
                                     int* __restrict__ ssrc, int e) {
    int i = blockIdx.x * blockDim.x + threadIdx.x;
    if (i < e) {
        int d = dst[i];
        int p = row_ptr[d] + atomicAdd(&cursor[d], 1);
        ssrc[p] = src[i];
    }
}

// ---------------- GEMM (128x128 weights, LDS-cached) ----------------
// block = 256 threads, 32 rows per block. thread: row = tid>>3, col quad base = (tid&7)*4,
// computes cols {cq, cq+32, cq+64, cq+96} (4x float4 accumulators).
template <bool SILU>
__global__ __launch_bounds__(256) void gemm_fc_kernel(
        const float* __restrict__ A, const float* __restrict__ W,
        const float* __restrict__ bias, float* __restrict__ out, int nrows) {
    __shared__ float sW[D * D];  // 64 KB
    {
        const float4* Wv = (const float4*)W;
        float4* sWv = (float4*)sW;
        for (int i = threadIdx.x; i < D * D / 4; i += 256) sWv[i] = Wv[i];
    }
    __syncthreads();

    int row = blockIdx.x * 32 + (threadIdx.x >> 3);
    if (row >= nrows) return;
    int cq = (threadIdx.x & 7) * 4;

    const float* Arow = A + (size_t)row * D;
    float4 acc[4] = {};

    for (int k = 0; k < D; k += 4) {
        float4 a4 = *(const float4*)(Arow + k);
        #pragma unroll
        for (int kk = 0; kk < 4; ++kk) {
            float a = ((const float*)&a4)[kk];
            const float* wr = sW + (k + kk) * D + cq;
            #pragma unroll
            for (int j = 0; j < 4; ++j) {
                float4 w = *(const float4*)(wr + j * 32);
                acc[j].x = fmaf(a, w.x, acc[j].x);
                acc[j].y = fmaf(a, w.y, acc[j].y);
                acc[j].z = fmaf(a, w.z, acc[j].z);
                acc[j].w = fmaf(a, w.w, acc[j].w);
            }
        }
    }

    size_t o = (size_t)row * D;
    #pragma unroll
    for (int j = 0; j < 4; ++j) {
        int c = cq + j * 32;
        float4 b = *(const float4*)(bias + c);
        float4 v;
        v.x = acc[j].x + b.x;
        v.y = acc[j].y + b.y;
        v.z = acc[j].z + b.z;
        v.w = acc[j].w + b.w;
        if (SILU) {
            v.x = silu_f(v.x); v.y = silu_f(v.y); v.z = silu_f(v.z); v.w = silu_f(v.w);
        }
        *(float4*)(out + o + c) = v;
    }
}

// ---------------- Horner diffusion step ----------------
// u_next = x + (inv_i / deg) * (A u)   — one wave per dst row, lane holds float2.
__global__ __launch_bounds__(256) void horner_step_kernel(
        const float* __restrict__ u, const float* __restrict__ x,
        float* __restrict__ u_next,
        const int* __restrict__ row_ptr, const int* __restrict__ ssrc,
        float inv_i, int nrows) {
    int gw = blockIdx.x * 4 + (threadIdx.x >> 6);
    if (gw >= nrows) return;
    int lane = threadIdx.x & 63;

    int beg = row_ptr[gw];
    int end = row_ptr[gw + 1];
    int deg = end - beg;

    float2 s = make_float2(0.f, 0.f);
    int j = beg;
    for (; j + 3 < end; j += 4) {
        int s0 = ssrc[j];
        int s1 = ssrc[j + 1];
        int s2 = ssrc[j + 2];
        int s3 = ssrc[j + 3];
        float2 v0 = *(const float2*)(u + (size_t)s0 * D + lane * 2);
        float2 v1 = *(const float2*)(u + (size_t)s1 * D + lane * 2);
        float2 v2 = *(const float2*)(u + (size_t)s2 * D + lane * 2);
        float2 v3 = *(const float2*)(u + (size_t)s3 * D + lane * 2);
        s.x += (v0.x + v1.x) + (v2.x + v3.x);
        s.y += (v0.y + v1.y) + (v2.y + v3.y);
    }
    for (; j < end; ++j) {
        int s0 = ssrc[j];
        float2 v0 = *(const float2*)(u + (size_t)s0 * D + lane * 2);
        s.x += v0.x;
        s.y += v0.y;
    }

    float scale = inv_i / (float)(deg > 1 ? deg : 1);
    size_t o = (size_t)gw * D + lane * 2;
    float2 xv = *(const float2*)(x + o);
    float2 r = make_float2(fmaf(s.x, scale, xv.x), fmaf(s.y, scale, xv.y));
    *(float2*)(u_next + o) = r;
}

// ---------------- launch ----------------

extern "C" void kernel_launch(void* const* d_in, const int* in_sizes, int n_in,
                              void* d_out, int out_size, void* d_ws, size_t ws_size,
                              hipStream_t stream) {
    const float* h      = (const float*)d_in[0];
    const int*   eidx   = (const int*)d_in[1];
    const float* W_in   = (const float*)d_in[2];
    const float* b_in   = (const float*)d_in[3];
    const float* W1     = (const float*)d_in[4];
    const float* b1     = (const float*)d_in[5];
    const float* W2     = (const float*)d_in[6];
    const float* b2     = (const float*)d_in[7];
    float* out = (float*)d_out;

    const int N = in_sizes[0] / D;      // 100000
    const int E = in_sizes[1] / 2;      // 1600000

    const int* e_src = eidx;
    const int* e_dst = eidx + E;

    // workspace layout
    float* X = (float*)d_ws;                       // N*D floats (silu(fc_in) output, constant)
    float* B = X + (size_t)N * D;                  // N*D floats (u ping buffer)
    int* deg     = (int*)(B + (size_t)N * D);      // N
    int* cursor  = deg + N;                        // N
    int* row_ptr = cursor + N;                     // N+1
    int* partials = row_ptr + N + 1;               // 256
    int* ssrc    = partials + 256;                 // E

    // zero deg + cursor (adjacent) in one memset
    hipMemsetAsync(deg, 0, sizeof(int) * (size_t)(2 * N), stream);

    const int nsb = (N + 511) / 512;               // scan blocks (196)
    int eb = (E + 255) / 256;
    count_deg_kernel<<<eb, 256, 0, stream>>>(e_dst, deg, E);
    scan_pass1_kernel<<<nsb, 512, 0, stream>>>(deg, row_ptr, partials, N);
    scan_pass2_kernel<<<1, 256, 0, stream>>>(partials, nsb);
    scan_pass3_kernel<<<nsb + 1, 512, 0, stream>>>(row_ptr, partials, N, E);
    scatter_edges_kernel<<<eb, 256, 0, stream>>>(e_src, e_dst, row_ptr, cursor, ssrc, E);

    int gb = (N + 31) / 32;
    // X = silu(h @ W_in + b_in)
    gemm_fc_kernel<true><<<gb, 256, 0, stream>>>(h, W_in, b_in, X, N);

    // Horner: u = X; for i = K..1: u = X + (A u)/i
    // ping-pong: X -> B -> out -> B -> out -> B -> out
    int db = (N + 3) / 4;
    const float* u_cur = X;
    float* bufs[2] = { B, out };
    int t = 0;
    for (int i = K_ORDER; i >= 1; --i) {
        float* u_nxt = bufs[t & 1];
        horner_step_kernel<<<db, 256, 0, stream>>>(u_cur, X, u_nxt, row_ptr, ssrc,
                                                   1.0f / (float)i, N);
        u_cur = u_nxt;
        ++t;
    }
    // u_cur == out here (6 steps end on 'out')

    // X2 = silu(u0 @ W1 + b1) -> reuse X buffer
    gemm_fc_kernel<true><<<gb, 256, 0, stream>>>(out, W1, b1, X, N);
    // out = X2 @ W2 + b2
    gemm_fc_kernel<false><<<gb, 256, 0, stream>>>(X, W2, b2, out, N);
}

// Round 3
// 948.664 us; speedup vs baseline: 1.4259x; 1.2299x over previous
//
#include <hip/hip_runtime.h>

#define D 128
#define K_ORDER 6

__device__ __forceinline__ float silu_f(float x) {
    return x / (1.0f + __expf(-x));
}

__device__ __forceinline__ unsigned pack_bf2(float lo, float hi) {
    unsigned ul = __float_as_uint(lo);
    unsigned uh = __float_as_uint(hi);
    ul = (ul + 0x7fffu + ((ul >> 16) & 1u)) >> 16;          // RNE
    uh = (uh + 0x7fffu + ((uh >> 16) & 1u)) & 0xffff0000u;  // RNE, keep high
    return uh | ul;
}

// ---------------- CSR build ----------------

__global__ void count_deg_kernel(const int* __restrict__ dst, int* __restrict__ deg, int e) {
    int i = blockIdx.x * blockDim.x + threadIdx.x;
    if (i < e) atomicAdd(&deg[dst[i]], 1);
}

__global__ __launch_bounds__(512) void scan_pass1_kernel(
        const int* __restrict__ deg, int* __restrict__ row_ptr,
        int* __restrict__ partials, int n) {
    __shared__ int lds[512];
    int i = blockIdx.x * 512 + threadIdx.x;
    int v = (i < n) ? deg[i] : 0;
    lds[threadIdx.x] = v;
    __syncthreads();
    #pragma unroll
    for (int off = 1; off < 512; off <<= 1) {
        int t = (threadIdx.x >= (unsigned)off) ? lds[threadIdx.x - off] : 0;
        __syncthreads();
        lds[threadIdx.x] += t;
        __syncthreads();
    }
    if (i < n) row_ptr[i] = lds[threadIdx.x] - v;   // exclusive
    if (threadIdx.x == 511) partials[blockIdx.x] = lds[511];
}

__global__ __launch_bounds__(256) void scan_pass2_kernel(int* __restrict__ partials, int np) {
    __shared__ int lds[256];
    int v = (threadIdx.x < (unsigned)np) ? partials[threadIdx.x] : 0;
    lds[threadIdx.x] = v;
    __syncthreads();
    #pragma unroll
    for (int off = 1; off < 256; off <<= 1) {
        int t = (threadIdx.x >= (unsigned)off) ? lds[threadIdx.x - off] : 0;
        __syncthreads();
        lds[threadIdx.x] += t;
        __syncthreads();
    }
    if (threadIdx.x < (unsigned)np) partials[threadIdx.x] = lds[threadIdx.x] - v;
}

__global__ __launch_bounds__(512) void scan_pass3_kernel(
        int* __restrict__ row_ptr, const int* __restrict__ partials, int n, int e) {
    int i = blockIdx.x * 512 + threadIdx.x;
    if (i < n) row_ptr[i] += partials[blockIdx.x];
    if (i == n) row_ptr[n] = e;
}

__global__ void scatter_edges_kernel(const int* __restrict__ src, const int* __restrict__ dst,
                                     const int* __restrict__ row_ptr, int* __restrict__ cursor,
                                     int* __restrict__ ssrc, int e) {
    int i = blockIdx.x * blockDim.x + threadIdx.x;
    if (i < e) {
        int d = dst[i];
        int p = row_ptr[d] + atomicAdd(&cursor[d], 1);
        ssrc[p] = src[i];
    }
}

// ---------------- GEMM: 128x128 weights in LDS, 4 rows x 8 cols per thread ----
// block = 256 threads -> 64 rows x 128 cols. thread: rt = tid>>4 (row group of 4),
// ct = tid&15 (col quad c0 = ct*4, plus c0+64). A read from global (16-lane
// broadcast, L1-served); W from LDS as b128. 1 B LDS / FMA -> FMA-bound.
template <bool SILU, bool DUP_BF>
__global__ __launch_bounds__(256) void gemm_rt_kernel(
        const float* __restrict__ A, const float* __restrict__ W,
        const float* __restrict__ bias, float* __restrict__ out,
        unsigned* __restrict__ out_bf, int nrows) {
    __shared__ float sW[D * D];  // 64 KB
    {
        const float4* Wv = (const float4*)W;
        float4* sWv = (float4*)sW;
        for (int i = threadIdx.x; i < D * D / 4; i += 256) sWv[i] = Wv[i];
    }
    __syncthreads();

    int ct = threadIdx.x & 15;
    int rt = threadIdx.x >> 4;
    int r0 = blockIdx.x * 64 + rt * 4;
    int c0 = ct * 4;

    float4 acc[4][2] = {};

    #pragma unroll 2
    for (int k = 0; k < D; k += 4) {
        float4 a[4];
        #pragma unroll
        for (int j = 0; j < 4; ++j) {
            int r = r0 + j;
            a[j] = (r < nrows) ? *(const float4*)(A + (size_t)r * D + k)
                               : make_float4(0.f, 0.f, 0.f, 0.f);
        }
        #pragma unroll
        for (int kk = 0; kk < 4; ++kk) {
            float4 wA = *(const float4*)(sW + (k + kk) * D + c0);
            float4 wB = *(const float4*)(sW + (k + kk) * D + c0 + 64);
            #pragma unroll
            for (int j = 0; j < 4; ++j) {
                float av = (&a[j].x)[kk];
                acc[j][0].x = fmaf(av, wA.x, acc[j][0].x);
                acc[j][0].y = fmaf(av, wA.y, acc[j][0].y);
                acc[j][0].z = fmaf(av, wA.z, acc[j][0].z);
                acc[j][0].w = fmaf(av, wA.w, acc[j][0].w);
                acc[j][1].x = fmaf(av, wB.x, acc[j][1].x);
                acc[j][1].y = fmaf(av, wB.y, acc[j][1].y);
                acc[j][1].z = fmaf(av, wB.z, acc[j][1].z);
                acc[j][1].w = fmaf(av, wB.w, acc[j][1].w);
            }
        }
    }

    float4 bA = *(const float4*)(bias + c0);
    float4 bB = *(const float4*)(bias + c0 + 64);
    #pragma unroll
    for (int j = 0; j < 4; ++j) {
        int r = r0 + j;
        if (r >= nrows) continue;
        float4 vA, vB;
        vA.x = acc[j][0].x + bA.x; vA.y = acc[j][0].y + bA.y;
        vA.z = acc[j][0].z + bA.z; vA.w = acc[j][0].w + bA.w;
        vB.x = acc[j][1].x + bB.x; vB.y = acc[j][1].y + bB.y;
        vB.z = acc[j][1].z + bB.z; vB.w = acc[j][1].w + bB.w;
        if (SILU) {
            vA.x = silu_f(vA.x); vA.y = silu_f(vA.y); vA.z = silu_f(vA.z); vA.w = silu_f(vA.w);
            vB.x = silu_f(vB.x); vB.y = silu_f(vB.y); vB.z = silu_f(vB.z); vB.w = silu_f(vB.w);
        }
        size_t o = (size_t)r * D;
        *(float4*)(out + o + c0) = vA;
        *(float4*)(out + o + c0 + 64) = vB;
        if (DUP_BF) {
            uint2 pA, pB;
            pA.x = pack_bf2(vA.x, vA.y); pA.y = pack_bf2(vA.z, vA.w);
            pB.x = pack_bf2(vB.x, vB.y); pB.y = pack_bf2(vB.z, vB.w);
            *(uint2*)(out_bf + (size_t)r * 64 + (c0 >> 1)) = pA;
            *(uint2*)(out_bf + (size_t)r * 64 + ((c0 + 64) >> 1)) = pB;
        }
    }
}

// ---------------- Horner diffusion step, bf16 state ----------------
// u_next = x + (inv_i / deg) * (A u). One wave per dst row; lane holds 2
// features as one packed bf16x2 uint (row = 256 B). Accumulate fp32.
template <bool FP32_OUT>
__global__ __launch_bounds__(256) void horner_bf_kernel(
        const unsigned* __restrict__ u, const float* __restrict__ x,
        void* __restrict__ u_next,
        const int* __restrict__ row_ptr, const int* __restrict__ ssrc,
        float inv_i, int nrows) {
    int gw = blockIdx.x * 4 + (threadIdx.x >> 6);
    if (gw >= nrows) return;
    int lane = threadIdx.x & 63;

    int beg = row_ptr[gw];
    int end = row_ptr[gw + 1];
    int deg = end - beg;

    float sx = 0.f, sy = 0.f;
    int j = beg;
    for (; j + 3 < end; j += 4) {
        int s0 = ssrc[j];
        int s1 = ssrc[j + 1];
        int s2 = ssrc[j + 2];
        int s3 = ssrc[j + 3];
        unsigned v0 = u[(size_t)s0 * 64 + lane];
        unsigned v1 = u[(size_t)s1 * 64 + lane];
        unsigned v2 = u[(size_t)s2 * 64 + lane];
        unsigned v3 = u[(size_t)s3 * 64 + lane];
        sx += __uint_as_float(v0 << 16) + __uint_as_float(v1 << 16)
            + __uint_as_float(v2 << 16) + __uint_as_float(v3 << 16);
        sy += __uint_as_float(v0 & 0xffff0000u) + __uint_as_float(v1 & 0xffff0000u)
            + __uint_as_float(v2 & 0xffff0000u) + __uint_as_float(v3 & 0xffff0000u);
    }
    for (; j < end; ++j) {
        unsigned v0 = u[(size_t)ssrc[j] * 64 + lane];
        sx += __uint_as_float(v0 << 16);
        sy += __uint_as_float(v0 & 0xffff0000u);
    }

    float scale = inv_i / (float)(deg > 1 ? deg : 1);
    size_t o = (size_t)gw * D + lane * 2;
    float2 xv = *(const float2*)(x + o);
    float rx = fmaf(sx, scale, xv.x);
    float ry = fmaf(sy, scale, xv.y);
    if (FP32_OUT) {
        float2 r = make_float2(rx, ry);
        *(float2*)((float*)u_next + o) = r;
    } else {
        ((unsigned*)u_next)[(size_t)gw * 64 + lane] = pack_bf2(rx, ry);
    }
}

// ---------------- launch ----------------

extern "C" void kernel_launch(void* const* d_in, const int* in_sizes, int n_in,
                              void* d_out, int out_size, void* d_ws, size_t ws_size,
                              hipStream_t stream) {
    const float* h      = (const float*)d_in[0];
    const int*   eidx   = (const int*)d_in[1];
    const float* W_in   = (const float*)d_in[2];
    const float* b_in   = (const float*)d_in[3];
    const float* W1     = (const float*)d_in[4];
    const float* b1     = (const float*)d_in[5];
    const float* W2     = (const float*)d_in[6];
    const float* b2     = (const float*)d_in[7];
    float* out = (float*)d_out;

    const int N = in_sizes[0] / D;      // 100000
    const int E = in_sizes[1] / 2;      // 1600000

    const int* e_src = eidx;
    const int* e_dst = eidx + E;

    // workspace layout
    float*    X   = (float*)d_ws;                       // N*D f32 (silu(fc_in), constant)
    unsigned* Ub0 = (unsigned*)(X + (size_t)N * D);     // N*64 uints (bf16x2 rows)
    unsigned* Ub1 = Ub0 + (size_t)N * 64;               // N*64 uints
    int* deg      = (int*)(Ub1 + (size_t)N * 64);       // N
    int* cursor   = deg + N;                            // N
    int* row_ptr  = cursor + N;                         // N+1
    int* partials = row_ptr + N + 1;                    // 256
    int* ssrc     = partials + 256;                     // E

    hipMemsetAsync(deg, 0, sizeof(int) * (size_t)(2 * N), stream);

    const int nsb = (N + 511) / 512;
    int eb = (E + 255) / 256;
    count_deg_kernel<<<eb, 256, 0, stream>>>(e_dst, deg, E);
    scan_pass1_kernel<<<nsb, 512, 0, stream>>>(deg, row_ptr, partials, N);
    scan_pass2_kernel<<<1, 256, 0, stream>>>(partials, nsb);
    scan_pass3_kernel<<<nsb + 1, 512, 0, stream>>>(row_ptr, partials, N, E);
    scatter_edges_kernel<<<eb, 256, 0, stream>>>(e_src, e_dst, row_ptr, cursor, ssrc, E);

    int gb = (N + 63) / 64;
    // X = silu(h @ W_in + b_in), plus bf16 copy into Ub0
    gemm_rt_kernel<true, true><<<gb, 256, 0, stream>>>(h, W_in, b_in, X, Ub0, N);

    // Horner: u = X; for i = K..1: u = X + (A u)/i  (bf16 state, final step fp32)
    int db = (N + 3) / 4;
    const unsigned* u_cur = Ub0;
    unsigned* bufs[2] = { Ub1, Ub0 };
    int t = 0;
    for (int i = K_ORDER; i >= 2; --i) {
        unsigned* u_nxt = bufs[t & 1];
        horner_bf_kernel<false><<<db, 256, 0, stream>>>(u_cur, X, u_nxt, row_ptr, ssrc,
                                                        1.0f / (float)i, N);
        u_cur = u_nxt;
        ++t;
    }
    // final step (i=1) -> fp32 into out
    horner_bf_kernel<true><<<db, 256, 0, stream>>>(u_cur, X, out, row_ptr, ssrc, 1.0f, N);

    // X2 = silu(u0 @ W1 + b1) -> reuse X
    gemm_rt_kernel<true, false><<<gb, 256, 0, stream>>>(out, W1, b1, X, nullptr, N);
    // out = X2 @ W2 + b2
    gemm_rt_kernel<false, false><<<gb, 256, 0, stream>>>(X, W2, b2, out, N ? out ? nullptr : nullptr : nullptr, N);
}

// Round 4
// 707.036 us; speedup vs baseline: 1.9132x; 1.3417x over previous
//
#include <hip/hip_runtime.h>

#define D 128
#define K_ORDER 6

typedef __attribute__((ext_vector_type(8))) short short8;
typedef __attribute__((ext_vector_type(4))) float f32x4;

__device__ __forceinline__ float silu_f(float x) {
    return x / (1.0f + __expf(-x));
}

__device__ __forceinline__ unsigned pack_bf2(float lo, float hi) {
    unsigned ul = __float_as_uint(lo);
    unsigned uh = __float_as_uint(hi);
    ul = (ul + 0x7fffu + ((ul >> 16) & 1u)) >> 16;          // RNE
    uh = (uh + 0x7fffu + ((uh >> 16) & 1u)) & 0xffff0000u;  // RNE, keep high
    return uh | ul;
}

__device__ __forceinline__ unsigned short bf16_of(float f) {
    unsigned u = __float_as_uint(f);
    u = (u + 0x7fffu + ((u >> 16) & 1u)) >> 16;
    return (unsigned short)u;
}

// ---------------- CSR build ----------------

__global__ void count_deg_kernel(const int* __restrict__ dst, int* __restrict__ deg, int e) {
    int i = blockIdx.x * blockDim.x + threadIdx.x;
    if (i < e) atomicAdd(&deg[dst[i]], 1);
}

__global__ __launch_bounds__(512) void scan_pass1_kernel(
        const int* __restrict__ deg, int* __restrict__ row_ptr,
        int* __restrict__ partials, int n) {
    __shared__ int lds[512];
    int i = blockIdx.x * 512 + threadIdx.x;
    int v = (i < n) ? deg[i] : 0;
    lds[threadIdx.x] = v;
    __syncthreads();
    #pragma unroll
    for (int off = 1; off < 512; off <<= 1) {
        int t = (threadIdx.x >= (unsigned)off) ? lds[threadIdx.x - off] : 0;
        __syncthreads();
        lds[threadIdx.x] += t;
        __syncthreads();
    }
    if (i < n) row_ptr[i] = lds[threadIdx.x] - v;   // exclusive
    if (threadIdx.x == 511) partials[blockIdx.x] = lds[511];
}

__global__ __launch_bounds__(256) void scan_pass2_kernel(int* __restrict__ partials, int np) {
    __shared__ int lds[256];
    int v = (threadIdx.x < (unsigned)np) ? partials[threadIdx.x] : 0;
    lds[threadIdx.x] = v;
    __syncthreads();
    #pragma unroll
    for (int off = 1; off < 256; off <<= 1) {
        int t = (threadIdx.x >= (unsigned)off) ? lds[threadIdx.x - off] : 0;
        __syncthreads();
        lds[threadIdx.x] += t;
        __syncthreads();
    }
    if (threadIdx.x < (unsigned)np) partials[threadIdx.x] = lds[threadIdx.x] - v;
}

__global__ __launch_bounds__(512) void scan_pass3_kernel(
        int* __restrict__ row_ptr, const int* __restrict__ partials, int n, int e) {
    int i = blockIdx.x * 512 + threadIdx.x;
    if (i < n) row_ptr[i] += partials[blockIdx.x];
    if (i == n) row_ptr[n] = e;
}

__global__ void scatter_edges_kernel(const int* __restrict__ src, const int* __restrict__ dst,
                                     const int* __restrict__ row_ptr, int* __restrict__ cursor,
                                     int* __restrict__ ssrc, int e) {
    int i = blockIdx.x * blockDim.x + threadIdx.x;
    if (i < e) {
        int d = dst[i];
        int p = row_ptr[d] + atomicAdd(&cursor[d], 1);
        ssrc[p] = src[i];
    }
}

// ---------------- MFMA GEMM: [nrows x 128] @ [128 x 128] ----------------
// Block = 256 thr = 4 waves; block tile 128 rows. Wave tile: 32 rows x 128 cols
// = 2x8 fragments of 16x16, K-loop 4 steps of 32.
// W^T staged in LDS as bf16 with +8 pad (conflict-free ds_read_b128).
// Fragment maps: A row = lane&15, k = (lane>>4)*8 + i ; B col = lane&15, same k;
// C/D col = lane&15, row = (lane>>4)*4 + reg  [m89-verified].
template <bool A_FP32, bool SILU, bool OUT_FP32>
__global__ __launch_bounds__(256) void gemm_mfma_kernel(
        const void* __restrict__ Ap, const float* __restrict__ W,
        const float* __restrict__ bias, void* __restrict__ outp, int nrows) {
    constexpr int LDW = 136;  // 128 + 8 bf16 pad
    __shared__ unsigned short sWt[128 * LDW];  // ~34.8 KB

    // stage W^T: read W[k][c] coalesced, write transposed
    for (int i = threadIdx.x; i < 128 * 128; i += 256) {
        int c = i & 127, k = i >> 7;
        sWt[c * LDW + k] = bf16_of(W[(size_t)k * 128 + c]);
    }
    __syncthreads();

    const int wave = threadIdx.x >> 6;
    const int lane = threadIdx.x & 63;
    const int lhi = lane >> 4;   // 0..3
    const int llo = lane & 15;   // 0..15

    const int rbase = blockIdx.x * 128 + wave * 32;

    f32x4 acc[2][8] = {};

    #pragma unroll
    for (int ks = 0; ks < 4; ++ks) {
        const int k0 = ks * 32 + lhi * 8;
        short8 afrag[2];
        #pragma unroll
        for (int rt = 0; rt < 2; ++rt) {
            int r = rbase + rt * 16 + llo;
            if (r < nrows) {
                if (A_FP32) {
                    const float* ap = (const float*)Ap + (size_t)r * 128 + k0;
                    float4 f0 = *(const float4*)ap;
                    float4 f1 = *(const float4*)(ap + 4);
                    union { unsigned u[4]; short8 s; } cvt;
                    cvt.u[0] = pack_bf2(f0.x, f0.y);
                    cvt.u[1] = pack_bf2(f0.z, f0.w);
                    cvt.u[2] = pack_bf2(f1.x, f1.y);
                    cvt.u[3] = pack_bf2(f1.z, f1.w);
                    afrag[rt] = cvt.s;
                } else {
                    afrag[rt] = *(const short8*)((const unsigned short*)Ap + (size_t)r * 128 + k0);
                }
            } else {
                afrag[rt] = short8{0, 0, 0, 0, 0, 0, 0, 0};
            }
        }
        #pragma unroll
        for (int ct = 0; ct < 8; ++ct) {
            short8 bfrag = *(const short8*)(sWt + (ct * 16 + llo) * LDW + k0);
            acc[0][ct] = __builtin_amdgcn_mfma_f32_16x16x32_bf16(afrag[0], bfrag, acc[0][ct], 0, 0, 0);
            acc[1][ct] = __builtin_amdgcn_mfma_f32_16x16x32_bf16(afrag[1], bfrag, acc[1][ct], 0, 0, 0);
        }
    }

    // bias per col-tile (uniform over rows)
    float bv[8];
    #pragma unroll
    for (int ct = 0; ct < 8; ++ct) bv[ct] = bias[ct * 16 + llo];

    #pragma unroll
    for (int rt = 0; rt < 2; ++rt) {
        int rb = rbase + rt * 16 + lhi * 4;
        #pragma unroll
        for (int reg = 0; reg < 4; ++reg) {
            int r = rb + reg;
            if (r >= nrows) continue;
            if (OUT_FP32) {
                float* orow = (float*)outp + (size_t)r * 128;
                #pragma unroll
                for (int ct = 0; ct < 8; ++ct) {
                    float v = acc[rt][ct][reg] + bv[ct];
                    if (SILU) v = silu_f(v);
                    orow[ct * 16 + llo] = v;
                }
            } else {
                unsigned short* orow = (unsigned short*)outp + (size_t)r * 128;
                #pragma unroll
                for (int ct = 0; ct < 8; ++ct) {
                    float v = acc[rt][ct][reg] + bv[ct];
                    if (SILU) v = silu_f(v);
                    orow[ct * 16 + llo] = bf16_of(v);
                }
            }
        }
    }
}

// ---------------- Horner diffusion step, all-bf16 ----------------
// u_next = x + (inv_i / deg) * (A u). One wave per dst row; lane holds 2
// features as one packed bf16x2 uint (row = 256 B). Accumulate fp32.
__global__ __launch_bounds__(256) void horner_bf_kernel(
        const unsigned* __restrict__ u, const unsigned* __restrict__ xb,
        unsigned* __restrict__ u_next,
        const int* __restrict__ row_ptr, const int* __restrict__ ssrc,
        float inv_i, int nrows) {
    int gw = blockIdx.x * 4 + (threadIdx.x >> 6);
    if (gw >= nrows) return;
    int lane = threadIdx.x & 63;

    int beg = row_ptr[gw];
    int end = row_ptr[gw + 1];
    int deg = end - beg;

    float sx = 0.f, sy = 0.f;
    int j = beg;
    for (; j + 3 < end; j += 4) {
        int s0 = ssrc[j];
        int s1 = ssrc[j + 1];
        int s2 = ssrc[j + 2];
        int s3 = ssrc[j + 3];
        unsigned v0 = u[(size_t)s0 * 64 + lane];
        unsigned v1 = u[(size_t)s1 * 64 + lane];
        unsigned v2 = u[(size_t)s2 * 64 + lane];
        unsigned v3 = u[(size_t)s3 * 64 + lane];
        sx += __uint_as_float(v0 << 16) + __uint_as_float(v1 << 16)
            + __uint_as_float(v2 << 16) + __uint_as_float(v3 << 16);
        sy += __uint_as_float(v0 & 0xffff0000u) + __uint_as_float(v1 & 0xffff0000u)
            + __uint_as_float(v2 & 0xffff0000u) + __uint_as_float(v3 & 0xffff0000u);
    }
    for (; j < end; ++j) {
        unsigned v0 = u[(size_t)ssrc[j] * 64 + lane];
        sx += __uint_as_float(v0 << 16);
        sy += __uint_as_float(v0 & 0xffff0000u);
    }

    float scale = inv_i / (float)(deg > 1 ? deg : 1);
    unsigned xv = xb[(size_t)gw * 64 + lane];
    float rx = fmaf(sx, scale, __uint_as_float(xv << 16));
    float ry = fmaf(sy, scale, __uint_as_float(xv & 0xffff0000u));
    u_next[(size_t)gw * 64 + lane] = pack_bf2(rx, ry);
}

// ---------------- launch ----------------

extern "C" void kernel_launch(void* const* d_in, const int* in_sizes, int n_in,
                              void* d_out, int out_size, void* d_ws, size_t ws_size,
                              hipStream_t stream) {
    const float* h      = (const float*)d_in[0];
    const int*   eidx   = (const int*)d_in[1];
    const float* W_in   = (const float*)d_in[2];
    const float* b_in   = (const float*)d_in[3];
    const float* W1     = (const float*)d_in[4];
    const float* b1     = (const float*)d_in[5];
    const float* W2     = (const float*)d_in[6];
    const float* b2     = (const float*)d_in[7];
    float* out = (float*)d_out;

    const int N = in_sizes[0] / D;      // 100000
    const int E = in_sizes[1] / 2;      // 1600000

    const int* e_src = eidx;
    const int* e_dst = eidx + E;

    // workspace layout (all bf16x2-packed uints for feature buffers)
    unsigned* Xb  = (unsigned*)d_ws;                    // N*64 (silu(fc_in), base+u0)
    unsigned* U0  = Xb + (size_t)N * 64;                // N*64
    unsigned* U1  = U0 + (size_t)N * 64;                // N*64
    int* deg      = (int*)(U1 + (size_t)N * 64);        // N
    int* cursor   = deg + N;                            // N
    int* row_ptr  = cursor + N;                         // N+1
    int* partials = row_ptr + N + 1;                    // 256
    int* ssrc     = partials + 256;                     // E

    hipMemsetAsync(deg, 0, sizeof(int) * (size_t)(2 * N), stream);

    const int nsb = (N + 511) / 512;
    int eb = (E + 255) / 256;
    count_deg_kernel<<<eb, 256, 0, stream>>>(e_dst, deg, E);
    scan_pass1_kernel<<<nsb, 512, 0, stream>>>(deg, row_ptr, partials, N);
    scan_pass2_kernel<<<1, 256, 0, stream>>>(partials, nsb);
    scan_pass3_kernel<<<nsb + 1, 512, 0, stream>>>(row_ptr, partials, N, E);
    scatter_edges_kernel<<<eb, 256, 0, stream>>>(e_src, e_dst, row_ptr, cursor, ssrc, E);

    int gb = (N + 127) / 128;
    // Xb = bf16(silu(h @ W_in + b_in))
    gemm_mfma_kernel<true, true, false><<<gb, 256, 0, stream>>>(h, W_in, b_in, Xb, N);

    // Horner: u = x; for i = K..1: u = x + (A u)/i   (all bf16)
    int db = (N + 3) / 4;
    horner_bf_kernel<<<db, 256, 0, stream>>>(Xb, Xb, U0, row_ptr, ssrc, 1.0f / 6.0f, N);
    horner_bf_kernel<<<db, 256, 0, stream>>>(U0, Xb, U1, row_ptr, ssrc, 1.0f / 5.0f, N);
    horner_bf_kernel<<<db, 256, 0, stream>>>(U1, Xb, U0, row_ptr, ssrc, 1.0f / 4.0f, N);
    horner_bf_kernel<<<db, 256, 0, stream>>>(U0, Xb, U1, row_ptr, ssrc, 1.0f / 3.0f, N);
    horner_bf_kernel<<<db, 256, 0, stream>>>(U1, Xb, U0, row_ptr, ssrc, 1.0f / 2.0f, N);
    horner_bf_kernel<<<db, 256, 0, stream>>>(U0, Xb, U1, row_ptr, ssrc, 1.0f, N);
    // final diffusion result: U1 (bf16)

    // U0 = bf16(silu(U1 @ W1 + b1))
    gemm_mfma_kernel<false, true, false><<<gb, 256, 0, stream>>>(U1, W1, b1, U0, N);
    // out = U0 @ W2 + b2  (fp32)
    gemm_mfma_kernel<false, false, true><<<gb, 256, 0, stream>>>(U0, W2, b2, out, N);
}

// Round 5
// 613.358 us; speedup vs baseline: 2.2054x; 1.1527x over previous
//
#include <hip/hip_runtime.h>

#define D 128
#define K_ORDER 6
#define NB_SHIFT 10          // bucket = dst >> 10
#define CPT 8                // edges per thread in bin_edges

typedef __attribute__((ext_vector_type(8))) short short8;
typedef __attribute__((ext_vector_type(4))) float f32x4;

__device__ __forceinline__ float silu_f(float x) {
    return x / (1.0f + __expf(-x));
}

__device__ __forceinline__ unsigned pack_bf2(float lo, float hi) {
    unsigned ul = __float_as_uint(lo);
    unsigned uh = __float_as_uint(hi);
    ul = (ul + 0x7fffu + ((ul >> 16) & 1u)) >> 16;          // RNE
    uh = (uh + 0x7fffu + ((uh >> 16) & 1u)) & 0xffff0000u;  // RNE, keep high
    return uh | ul;
}

__device__ __forceinline__ unsigned short bf16_of(float f) {
    unsigned u = __float_as_uint(f);
    u = (u + 0x7fffu + ((u >> 16) & 1u)) >> 16;
    return (unsigned short)u;
}

// ---------------- CSR build ----------------

__global__ void count_deg_kernel(const int* __restrict__ dst, int* __restrict__ deg, int e) {
    int i = blockIdx.x * blockDim.x + threadIdx.x;
    if (i < e) atomicAdd(&deg[dst[i]], 1);
}

__global__ __launch_bounds__(512) void scan_pass1_kernel(
        const int* __restrict__ deg, int* __restrict__ row_ptr,
        int* __restrict__ partials, int n) {
    __shared__ int lds[512];
    int i = blockIdx.x * 512 + threadIdx.x;
    int v = (i < n) ? deg[i] : 0;
    lds[threadIdx.x] = v;
    __syncthreads();
    #pragma unroll
    for (int off = 1; off < 512; off <<= 1) {
        int t = (threadIdx.x >= (unsigned)off) ? lds[threadIdx.x - off] : 0;
        __syncthreads();
        lds[threadIdx.x] += t;
        __syncthreads();
    }
    if (i < n) row_ptr[i] = lds[threadIdx.x] - v;   // exclusive
    if (threadIdx.x == 511) partials[blockIdx.x] = lds[511];
}

__global__ __launch_bounds__(256) void scan_pass2_kernel(int* __restrict__ partials, int np) {
    __shared__ int lds[256];
    int v = (threadIdx.x < (unsigned)np) ? partials[threadIdx.x] : 0;
    lds[threadIdx.x] = v;
    __syncthreads();
    #pragma unroll
    for (int off = 1; off < 256; off <<= 1) {
        int t = (threadIdx.x >= (unsigned)off) ? lds[threadIdx.x - off] : 0;
        __syncthreads();
        lds[threadIdx.x] += t;
        __syncthreads();
    }
    if (threadIdx.x < (unsigned)np) partials[threadIdx.x] = lds[threadIdx.x] - v;
}

__global__ __launch_bounds__(512) void scan_pass3_kernel(
        int* __restrict__ row_ptr, const int* __restrict__ partials, int n, int e) {
    int i = blockIdx.x * 512 + threadIdx.x;
    if (i < n) row_ptr[i] += partials[blockIdx.x];
    if (i == n) row_ptr[n] = e;
}

// bin cursors start at each bucket's region start (from row_ptr)
__global__ void init_bin_cursor_kernel(const int* __restrict__ row_ptr,
                                       int* __restrict__ bin_cur, int nb) {
    int b = threadIdx.x;
    if (b < nb) bin_cur[b] = row_ptr[b << NB_SHIFT];
}

// Phase 1: bin edges by dst>>NB_SHIFT into bucket-contiguous (src,dst) chunks.
// Block-local LDS histogram -> one global chunk reservation per (block,bucket).
__global__ __launch_bounds__(256) void bin_edges_kernel(
        const int* __restrict__ src, const int* __restrict__ dst,
        int* __restrict__ bin_cur, uint2* __restrict__ binned, int e, int nb) {
    __shared__ int hist[128];
    __shared__ int base[128];
    for (int i = threadIdx.x; i < 128; i += 256) hist[i] = 0;
    __syncthreads();

    int e0 = blockIdx.x * (256 * CPT) + threadIdx.x;
    int myb[CPT], myoff[CPT], mysrc[CPT], mydst[CPT];
    #pragma unroll
    for (int k = 0; k < CPT; ++k) {
        int idx = e0 + k * 256;
        bool ok = idx < e;
        int d = ok ? dst[idx] : 0;
        int s = ok ? src[idx] : 0;
        int b = d >> NB_SHIFT;
        int off = ok ? atomicAdd(&hist[b], 1) : 0;
        myb[k] = b; myoff[k] = off; mysrc[k] = s; mydst[k] = d;
    }
    __syncthreads();
    for (int i = threadIdx.x; i < nb; i += 256) {
        int h = hist[i];
        base[i] = h ? atomicAdd(&bin_cur[i], h) : 0;
    }
    __syncthreads();
    #pragma unroll
    for (int k = 0; k < CPT; ++k) {
        int idx = e0 + k * 256;
        if (idx < e)
            binned[(size_t)base[myb[k]] + myoff[k]] =
                make_uint2((unsigned)mysrc[k], (unsigned)mydst[k]);
    }
}

// Phase 2: within each bucket, final scatter. Bucket's ssrc window (~65 KB)
// stays L2-resident; one block per bucket keeps it on one XCD.
__global__ __launch_bounds__(1024) void bucket_scatter_kernel(
        const uint2* __restrict__ binned, const int* __restrict__ row_ptr,
        int* __restrict__ cursor, int* __restrict__ ssrc, int nb, int n) {
    int b = blockIdx.x;
    int node0 = b << NB_SHIFT;
    int node1 = ((b + 1) << NB_SHIFT); if (node1 > n) node1 = n;
    int beg = row_ptr[node0];
    int end = row_ptr[node1];
    for (int j = beg + (int)threadIdx.x; j < end; j += 1024) {
        uint2 eg = binned[j];
        int d = (int)eg.y;
        int p = row_ptr[d] + atomicAdd(&cursor[d], 1);
        ssrc[p] = (int)eg.x;
    }
}

// ---------------- MFMA GEMM: [nrows x 128] @ [128 x 128] ----------------
template <bool A_FP32, bool SILU, bool OUT_FP32>
__global__ __launch_bounds__(256) void gemm_mfma_kernel(
        const void* __restrict__ Ap, const float* __restrict__ W,
        const float* __restrict__ bias, void* __restrict__ outp, int nrows) {
    constexpr int LDW = 136;  // 128 + 8 bf16 pad
    __shared__ unsigned short sWt[128 * LDW];  // ~34.8 KB

    for (int i = threadIdx.x; i < 128 * 128; i += 256) {
        int c = i & 127, k = i >> 7;
        sWt[c * LDW + k] = bf16_of(W[(size_t)k * 128 + c]);
    }
    __syncthreads();

    const int wave = threadIdx.x >> 6;
    const int lane = threadIdx.x & 63;
    const int lhi = lane >> 4;
    const int llo = lane & 15;

    const int rbase = blockIdx.x * 128 + wave * 32;

    f32x4 acc[2][8] = {};

    #pragma unroll
    for (int ks = 0; ks < 4; ++ks) {
        const int k0 = ks * 32 + lhi * 8;
        short8 afrag[2];
        #pragma unroll
        for (int rt = 0; rt < 2; ++rt) {
            int r = rbase + rt * 16 + llo;
            if (r < nrows) {
                if (A_FP32) {
                    const float* ap = (const float*)Ap + (size_t)r * 128 + k0;
                    float4 f0 = *(const float4*)ap;
                    float4 f1 = *(const float4*)(ap + 4);
                    union { unsigned u[4]; short8 s; } cvt;
                    cvt.u[0] = pack_bf2(f0.x, f0.y);
                    cvt.u[1] = pack_bf2(f0.z, f0.w);
                    cvt.u[2] = pack_bf2(f1.x, f1.y);
                    cvt.u[3] = pack_bf2(f1.z, f1.w);
                    afrag[rt] = cvt.s;
                } else {
                    afrag[rt] = *(const short8*)((const unsigned short*)Ap + (size_t)r * 128 + k0);
                }
            } else {
                afrag[rt] = short8{0, 0, 0, 0, 0, 0, 0, 0};
            }
        }
        #pragma unroll
        for (int ct = 0; ct < 8; ++ct) {
            short8 bfrag = *(const short8*)(sWt + (ct * 16 + llo) * LDW + k0);
            acc[0][ct] = __builtin_amdgcn_mfma_f32_16x16x32_bf16(afrag[0], bfrag, acc[0][ct], 0, 0, 0);
            acc[1][ct] = __builtin_amdgcn_mfma_f32_16x16x32_bf16(afrag[1], bfrag, acc[1][ct], 0, 0, 0);
        }
    }

    float bv[8];
    #pragma unroll
    for (int ct = 0; ct < 8; ++ct) bv[ct] = bias[ct * 16 + llo];

    #pragma unroll
    for (int rt = 0; rt < 2; ++rt) {
        int rb = rbase + rt * 16 + lhi * 4;
        #pragma unroll
        for (int reg = 0; reg < 4; ++reg) {
            int r = rb + reg;
            if (r >= nrows) continue;
            if (OUT_FP32) {
                float* orow = (float*)outp + (size_t)r * 128;
                #pragma unroll
                for (int ct = 0; ct < 8; ++ct) {
                    float v = acc[rt][ct][reg] + bv[ct];
                    if (SILU) v = silu_f(v);
                    orow[ct * 16 + llo] = v;
                }
            } else {
                unsigned short* orow = (unsigned short*)outp + (size_t)r * 128;
                #pragma unroll
                for (int ct = 0; ct < 8; ++ct) {
                    float v = acc[rt][ct][reg] + bv[ct];
                    if (SILU) v = silu_f(v);
                    orow[ct * 16 + llo] = bf16_of(v);
                }
            }
        }
    }
}

// ---------------- Horner diffusion step, all-bf16 ----------------
// u_next = x + (inv_i / deg) * (A u). 2 dst rows per wave (32 lanes each);
// lane reads uint2 = 4 bf16 features (8 B) per gathered row. fp32 accumulate.
__global__ __launch_bounds__(256) void horner_bf_kernel(
        const uint2* __restrict__ u, const uint2* __restrict__ xb,
        uint2* __restrict__ u_next,
        const int* __restrict__ row_ptr, const int* __restrict__ ssrc,
        float inv_i, int nrows) {
    int wave = threadIdx.x >> 6;
    int lane = threadIdx.x & 63;
    int sub = lane >> 5;
    int sl = lane & 31;
    int gw = blockIdx.x * 8 + wave * 2 + sub;
    if (gw >= nrows) return;

    int beg = row_ptr[gw];
    int end = row_ptr[gw + 1];
    int deg = end - beg;

    float s0 = 0.f, s1 = 0.f, s2 = 0.f, s3 = 0.f;
    int j = beg;
    for (; j + 3 < end; j += 4) {
        int a0 = ssrc[j];
        int a1 = ssrc[j + 1];
        int a2 = ssrc[j + 2];
        int a3 = ssrc[j + 3];
        uint2 v0 = u[(size_t)a0 * 32 + sl];
        uint2 v1 = u[(size_t)a1 * 32 + sl];
        uint2 v2 = u[(size_t)a2 * 32 + sl];
        uint2 v3 = u[(size_t)a3 * 32 + sl];
        s0 += __uint_as_float(v0.x << 16) + __uint_as_float(v1.x << 16)
            + __uint_as_float(v2.x << 16) + __uint_as_float(v3.x << 16);
        s1 += __uint_as_float(v0.x & 0xffff0000u) + __uint_as_float(v1.x & 0xffff0000u)
            + __uint_as_float(v2.x & 0xffff0000u) + __uint_as_float(v3.x & 0xffff0000u);
        s2 += __uint_as_float(v0.y << 16) + __uint_as_float(v1.y << 16)
            + __uint_as_float(v2.y << 16) + __uint_as_float(v3.y << 16);
        s3 += __uint_as_float(v0.y & 0xffff0000u) + __uint_as_float(v1.y & 0xffff0000u)
            + __uint_as_float(v2.y & 0xffff0000u) + __uint_as_float(v3.y & 0xffff0000u);
    }
    for (; j < end; ++j) {
        uint2 v0 = u[(size_t)ssrc[j] * 32 + sl];
        s0 += __uint_as_float(v0.x << 16);
        s1 += __uint_as_float(v0.x & 0xffff0000u);
        s2 += __uint_as_float(v0.y << 16);
        s3 += __uint_as_float(v0.y & 0xffff0000u);
    }

    float scale = inv_i / (float)(deg > 1 ? deg : 1);
    uint2 xv = xb[(size_t)gw * 32 + sl];
    float r0 = fmaf(s0, scale, __uint_as_float(xv.x << 16));
    float r1 = fmaf(s1, scale, __uint_as_float(xv.x & 0xffff0000u));
    float r2 = fmaf(s2, scale, __uint_as_float(xv.y << 16));
    float r3 = fmaf(s3, scale, __uint_as_float(xv.y & 0xffff0000u));
    u_next[(size_t)gw * 32 + sl] = make_uint2(pack_bf2(r0, r1), pack_bf2(r2, r3));
}

// ---------------- launch ----------------

extern "C" void kernel_launch(void* const* d_in, const int* in_sizes, int n_in,
                              void* d_out, int out_size, void* d_ws, size_t ws_size,
                              hipStream_t stream) {
    const float* h      = (const float*)d_in[0];
    const int*   eidx   = (const int*)d_in[1];
    const float* W_in   = (const float*)d_in[2];
    const float* b_in   = (const float*)d_in[3];
    const float* W1     = (const float*)d_in[4];
    const float* b1     = (const float*)d_in[5];
    const float* W2     = (const float*)d_in[6];
    const float* b2     = (const float*)d_in[7];
    float* out = (float*)d_out;

    const int N = in_sizes[0] / D;      // 100000
    const int E = in_sizes[1] / 2;      // 1600000
    const int NB = (N + (1 << NB_SHIFT) - 1) >> NB_SHIFT;   // 98 buckets

    const int* e_src = eidx;
    const int* e_dst = eidx + E;

    // workspace layout
    unsigned* Xb   = (unsigned*)d_ws;                   // N*64 (bf16x2 rows)
    unsigned* U0   = Xb + (size_t)N * 64;               // N*64
    unsigned* U1   = U0 + (size_t)N * 64;               // N*64
    uint2*    binned = (uint2*)(U1 + (size_t)N * 64);   // E uint2 (8B-aligned)
    int* ssrc     = (int*)(binned + E);                 // E
    int* deg      = ssrc + E;                           // N
    int* cursor   = deg + N;                            // N
    int* row_ptr  = cursor + N;                         // N+1
    int* partials = row_ptr + N + 1;                    // 256
    int* bin_cur  = partials + 256;                     // 128

    hipMemsetAsync(deg, 0, sizeof(int) * (size_t)(2 * N), stream);

    const int nsb = (N + 511) / 512;
    int eb = (E + 255) / 256;
    count_deg_kernel<<<eb, 256, 0, stream>>>(e_dst, deg, E);
    scan_pass1_kernel<<<nsb, 512, 0, stream>>>(deg, row_ptr, partials, N);
    scan_pass2_kernel<<<1, 256, 0, stream>>>(partials, nsb);
    scan_pass3_kernel<<<nsb + 1, 512, 0, stream>>>(row_ptr, partials, N, E);
    init_bin_cursor_kernel<<<1, 128, 0, stream>>>(row_ptr, bin_cur, NB);
    int bb = (E + 256 * CPT - 1) / (256 * CPT);
    bin_edges_kernel<<<bb, 256, 0, stream>>>(e_src, e_dst, bin_cur, binned, E, NB);
    bucket_scatter_kernel<<<NB, 1024, 0, stream>>>(binned, row_ptr, cursor, ssrc, NB, N);

    int gb = (N + 127) / 128;
    // Xb = bf16(silu(h @ W_in + b_in))
    gemm_mfma_kernel<true, true, false><<<gb, 256, 0, stream>>>(h, W_in, b_in, Xb, N);

    // Horner: u = x; for i = K..1: u = x + (A u)/i   (all bf16)
    int db = (N + 7) / 8;
    const uint2* Xb2 = (const uint2*)Xb;
    uint2* U0v = (uint2*)U0;
    uint2* U1v = (uint2*)U1;
    horner_bf_kernel<<<db, 256, 0, stream>>>(Xb2, Xb2, U0v, row_ptr, ssrc, 1.0f / 6.0f, N);
    horner_bf_kernel<<<db, 256, 0, stream>>>(U0v, Xb2, U1v, row_ptr, ssrc, 1.0f / 5.0f, N);
    horner_bf_kernel<<<db, 256, 0, stream>>>(U1v, Xb2, U0v, row_ptr, ssrc, 1.0f / 4.0f, N);
    horner_bf_kernel<<<db, 256, 0, stream>>>(U0v, Xb2, U1v, row_ptr, ssrc, 1.0f / 3.0f, N);
    horner_bf_kernel<<<db, 256, 0, stream>>>(U1v, Xb2, U0v, row_ptr, ssrc, 1.0f / 2.0f, N);
    horner_bf_kernel<<<db, 256, 0, stream>>>(U0v, Xb2, U1v, row_ptr, ssrc, 1.0f, N);
    // final diffusion result: U1 (bf16)

    // U0 = bf16(silu(U1 @ W1 + b1))
    gemm_mfma_kernel<false, true, false><<<gb, 256, 0, stream>>>(U1, W1, b1, U0, N);
    // out = U0 @ W2 + b2  (fp32)
    gemm_mfma_kernel<false, false, true><<<gb, 256, 0, stream>>>(U0, W2, b2, out, N);
}